// Round 16
// baseline (119.929 us; speedup 1.0000x reference)
//
#include <hip/hip_runtime.h>

#define DD 128
#define KADJ 12
#define BN_TOTAL 12800

typedef float f32x4 __attribute__((ext_vector_type(4)));
typedef float f32x2 __attribute__((ext_vector_type(2)));
typedef __bf16 bf16x8 __attribute__((ext_vector_type(8)));

__device__ __forceinline__ bf16x8 cvt8(f32x4 a, f32x4 b) {
    bf16x8 r;
    r[0] = (__bf16)a[0]; r[1] = (__bf16)a[1]; r[2] = (__bf16)a[2]; r[3] = (__bf16)a[3];
    r[4] = (__bf16)b[0]; r[5] = (__bf16)b[1]; r[6] = (__bf16)b[2]; r[7] = (__bf16)b[3];
    return r;
}

// ---- K0: shuffle w1 (rows 0..127) and w3 into MFMA B-fragment order, bf16 ----
__global__ void k_prep(const float* __restrict__ w1, const float* __restrict__ w3,
                       __bf16* __restrict__ w1f, __bf16* __restrict__ w3f) {
    int idx = blockIdx.x * 256 + threadIdx.x;   // 0..49151
    int lane = (idx >> 3) & 63, e = idx & 7;
    int l = lane & 15, gg = lane >> 4;
    if (idx < 16384) {
        int fi = idx >> 9, n = fi >> 2, ks = fi & 3;
        int k = ks * 32 + gg * 8 + e;
        w1f[idx] = (__bf16)w1[k * DD + n * 16 + l];
    } else {
        int j = idx - 16384;
        int fi = j >> 9, n = fi >> 3, ks = fi & 7;
        int k = ks * 32 + gg * 8 + e;
        w3f[j] = (__bf16)w3[k * DD + n * 16 + l];
    }
}

// ---- per-bn body: consume prefetched adj regs, MFMA (B via DS), epilogue,
// ---- softmax, att via global re-read (L1/L2-hot: same lines as the gather) ----
__device__ __forceinline__ void process_bn(
    const f32x4 P[8], f32x4 WG, int BN, int lane, int l, int g,
    const __bf16* w1s, const float* w2s, const float* w1rs,
    const float* __restrict__ ave, const float* __restrict__ adj,
    float* __restrict__ att_out) {

    // A-frags: fold ave (f32 mul, single rounding)
    const float* er = ave + (size_t)BN * DD + g * 8;
    bf16x8 af[4];
    #pragma unroll
    for (int s = 0; s < 4; ++s) {
        f32x4 e0 = *reinterpret_cast<const f32x4*>(er + s * 32);
        f32x4 e1 = *reinterpret_cast<const f32x4*>(er + s * 32 + 4);
        af[s] = cvt8(P[2 * s] * e0, P[2 * s + 1] * e1);
    }

    // 32 MFMA, B-frags via DS pipe
    f32x4 acc[8];
    #pragma unroll
    for (int n = 0; n < 8; ++n) acc[n] = f32x4{0.f, 0.f, 0.f, 0.f};
    const __bf16* wb = w1s + lane * 8;
    #pragma unroll
    for (int ks = 0; ks < 4; ++ks)
        #pragma unroll
        for (int n = 0; n < 8; ++n) {
            bf16x8 bq = *reinterpret_cast<const bf16x8*>(wb + (size_t)(n * 4 + ks) * 512);
            acc[n] = __builtin_amdgcn_mfma_f32_16x16x32_bf16(af[ks], bq, acc[n], 0, 0, 0);
        }

    // epilogue: rank-1 wgt col, leaky, dot w2 (operands from LDS)
    float p[4] = {0.f, 0.f, 0.f, 0.f};
    #pragma unroll
    for (int n = 0; n < 8; ++n) {
        float w1rn = w1rs[n * 16 + l];
        float w2vn = w2s[n * 16 + l];
        #pragma unroll
        for (int j = 0; j < 4; ++j) {
            float h = fmaf(WG[j], w1rn, acc[n][j]);
            h = h > 0.f ? h : 0.2f * h;
            p[j] = fmaf(h, w2vn, p[j]);
        }
    }
    #pragma unroll
    for (int j = 0; j < 4; ++j) {
        p[j] += __shfl_xor(p[j], 1, 64);
        p[j] += __shfl_xor(p[j], 2, 64);
        p[j] += __shfl_xor(p[j], 4, 64);
        p[j] += __shfl_xor(p[j], 8, 64);
        if (g == 3) p[j] = -1e30f;               // pad rows 12..15 out of softmax
    }
    float q0[4], q1[4], q2[4];
    #pragma unroll
    for (int j = 0; j < 4; ++j) {
        q0[j] = __shfl_xor(p[j], 16, 64);
        q1[j] = __shfl_xor(p[j], 32, 64);
        q2[j] = __shfl_xor(q1[j], 16, 64);
    }
    float mx = -1e30f;
    #pragma unroll
    for (int j = 0; j < 4; ++j)
        mx = fmaxf(mx, fmaxf(fmaxf(p[j], q0[j]), fmaxf(q1[j], q2[j])));
    float ssum = 0.f;
    #pragma unroll
    for (int j = 0; j < 4; ++j) {
        ssum += __expf(p[j] - mx);  ssum += __expf(q0[j] - mx);
        ssum += __expf(q1[j] - mx); ssum += __expf(q2[j] - mx);
    }
    float inv = 1.f / ssum;

    // att: lanes = columns; adj re-read coalesced (lines are L1/L2-hot)
    const float* adjp = adj + (size_t)BN * (KADJ * DD);
    float a0 = 0.f, a1 = 0.f;
    #pragma unroll
    for (int k = 0; k < KADJ; ++k) {
        int d = (k >> 2) ^ g, j = k & 3;
        float sv = (d == 0) ? p[j] : (d == 1) ? q0[j] : (d == 2) ? q1[j] : q2[j];
        float alpha = __expf(sv - mx) * inv;
        a0 = fmaf(alpha, adjp[k * DD + lane], a0);
        a1 = fmaf(alpha, adjp[k * DD + 64 + lane], a1);
    }
    att_out[(size_t)BN * DD + lane] = a0;
    att_out[(size_t)BN * DD + 64 + lane] = a1;
}

// ---- K1: 2 bn per wave, both gather batches issued up front (2-deep pipeline);
// single barrier (w1/w2 LDS staging); B-frags via DS pipe; grid fills the chip.
__launch_bounds__(256, 4)
__global__ void k_att(const float* __restrict__ ave, const float* __restrict__ adj,
                      const float* __restrict__ wgt, const float* __restrict__ w1,
                      const float* __restrict__ w2, const __bf16* __restrict__ w1f,
                      float* __restrict__ att_out) {
    __shared__ __bf16 w1s[16384];              // 32 KB fragment-ordered w1
    __shared__ float w2s[128];
    __shared__ float w1rs[128];                // w1 row 128 (concat'd wgt row)

    const int t = threadIdx.x;
    const int lane = t & 63;
    const int w = t >> 6;
    const int l = lane & 15, g = lane >> 4;
    const int bn0 = blockIdx.x * 8 + w * 2;

    // ---- stage w1f + epilogue operands -> LDS; the ONLY barrier ----
    {
        const f32x4* src = (const f32x4*)w1f;
        f32x4* dst = (f32x4*)w1s;
        #pragma unroll
        for (int p = 0; p < 8; ++p) dst[p * 256 + t] = src[p * 256 + t];
        if (t < 128) { w2s[t] = w2[t]; w1rs[t] = w1[128 * DD + t]; }
    }
    __syncthreads();

    const int l2 = l < KADJ ? l : KADJ - 1;    // clamp pad rows

    // ---- issue BOTH bn's gathers up front (18 outstanding VMEM ops) ----
    f32x4 paA[8], paB[8], wgA, wgB;
    {
        const float* ar = adj + ((size_t)bn0 * KADJ + l2) * DD + g * 8;
        #pragma unroll
        for (int s = 0; s < 4; ++s) {
            paA[2 * s]     = *reinterpret_cast<const f32x4*>(ar + s * 32);
            paA[2 * s + 1] = *reinterpret_cast<const f32x4*>(ar + s * 32 + 4);
        }
        wgA = (g < 3) ? *reinterpret_cast<const f32x4*>(wgt + (size_t)bn0 * KADJ + g * 4)
                      : f32x4{0.f, 0.f, 0.f, 0.f};
    }
    {
        const float* ar = adj + ((size_t)(bn0 + 1) * KADJ + l2) * DD + g * 8;
        #pragma unroll
        for (int s = 0; s < 4; ++s) {
            paB[2 * s]     = *reinterpret_cast<const f32x4*>(ar + s * 32);
            paB[2 * s + 1] = *reinterpret_cast<const f32x4*>(ar + s * 32 + 4);
        }
        wgB = (g < 3) ? *reinterpret_cast<const f32x4*>(wgt + (size_t)(bn0 + 1) * KADJ + g * 4)
                      : f32x4{0.f, 0.f, 0.f, 0.f};
    }

    // ---- process bn0 (bn1's loads land underneath), then bn1 ----
    process_bn(paA, wgA, bn0,     lane, l, g, w1s, w2s, w1rs, ave, adj, att_out);
    process_bn(paB, wgB, bn0 + 1, lane, l, g, w1s, w2s, w1rs, ave, adj, att_out);
}

// ---- K2: out = relu([itm | att] @ w3) via MFMA; B-frags coalesced from w3f ----
__launch_bounds__(256)
__global__ void k_out(const float* __restrict__ itm, const float* att,
                      const __bf16* __restrict__ w3f, float* outp) {
    const int t = threadIdx.x;
    const int lane = t & 63;
    const int w = t >> 6;
    const int l = lane & 15, g = lane >> 4;
    const int R0 = blockIdx.x * 64 + w * 16;
    const int row = R0 + l;

    bf16x8 afr[8];
    const float* ip = itm + (size_t)row * DD;
    #pragma unroll
    for (int s = 0; s < 4; ++s) {
        int c = s * 32 + g * 8;
        f32x4 a0 = *reinterpret_cast<const f32x4*>(ip + c);
        f32x4 a1 = *reinterpret_cast<const f32x4*>(ip + c + 4);
        afr[s] = cvt8(a0, a1);
    }
    const float* ap = att + (size_t)row * DD;
    #pragma unroll
    for (int s = 0; s < 4; ++s) {
        int c = s * 32 + g * 8;
        f32x4 a0 = *reinterpret_cast<const f32x4*>(ap + c);
        f32x4 a1 = *reinterpret_cast<const f32x4*>(ap + c + 4);
        afr[4 + s] = cvt8(a0, a1);
    }

    f32x4 acc[8];
    #pragma unroll
    for (int n = 0; n < 8; ++n) acc[n] = f32x4{0.f, 0.f, 0.f, 0.f};
    #pragma unroll
    for (int s = 0; s < 8; ++s) {
        const __bf16* bp = w3f + ((size_t)s * 64 + lane) * 8;    // coalesced 1KB/wave
        #pragma unroll
        for (int n = 0; n < 8; ++n) {
            bf16x8 bfr = *reinterpret_cast<const bf16x8*>(bp + (size_t)n * 4096);
            acc[n] = __builtin_amdgcn_mfma_f32_16x16x32_bf16(afr[s], bfr, acc[n], 0, 0, 0);
        }
    }

    #pragma unroll
    for (int n = 0; n < 8; ++n) {
        #pragma unroll
        for (int j = 0; j < 4; ++j)
            outp[(size_t)(R0 + g * 4 + j) * DD + n * 16 + l] = fmaxf(acc[n][j], 0.f);
    }
}

extern "C" void kernel_launch(void* const* d_in, const int* in_sizes, int n_in,
                              void* d_out, int out_size, void* d_ws, size_t ws_size,
                              hipStream_t stream) {
    const float* itm = (const float*)d_in[1];
    const float* ave = (const float*)d_in[2];
    const float* adj = (const float*)d_in[3];
    const float* wgt = (const float*)d_in[4];
    const float* w1  = (const float*)d_in[5];
    const float* w2  = (const float*)d_in[6];
    const float* w3  = (const float*)d_in[7];
    float* outp = (float*)d_out;

    __bf16* w1f = (__bf16*)d_ws;                       // 32 KB, fragment-ordered
    __bf16* w3f = (__bf16*)((char*)d_ws + 32 * 1024);  // 64 KB, fragment-ordered

    k_prep<<<dim3(192), dim3(256), 0, stream>>>(w1, w3, w1f, w3f);
    k_att<<<dim3(BN_TOTAL / 8), dim3(256), 0, stream>>>(ave, adj, wgt, w1, w2, w1f, outp);
    k_out<<<dim3(BN_TOTAL / 64), dim3(256), 0, stream>>>(itm, outp, w3f, outp);
}

// Round 17
// 46.285 us; speedup vs baseline: 2.5911x; 2.5911x over previous
//
#include <hip/hip_runtime.h>

#define DD 128
#define KADJ 12
#define BN_TOTAL 12800

typedef float f32x4 __attribute__((ext_vector_type(4)));
typedef float f32x2 __attribute__((ext_vector_type(2)));
typedef __bf16 bf16x8 __attribute__((ext_vector_type(8)));
typedef unsigned int u32;

__device__ __forceinline__ bf16x8 cvt8(f32x4 a, f32x4 b) {
    bf16x8 r;
    r[0] = (__bf16)a[0]; r[1] = (__bf16)a[1]; r[2] = (__bf16)a[2]; r[3] = (__bf16)a[3];
    r[4] = (__bf16)b[0]; r[5] = (__bf16)b[1]; r[6] = (__bf16)b[2]; r[7] = (__bf16)b[3];
    return r;
}

// ---- K0: shuffle w1 (rows 0..127) and w3 into MFMA B-fragment order, bf16 ----
__global__ void k_prep(const float* __restrict__ w1, const float* __restrict__ w3,
                       __bf16* __restrict__ w1f, __bf16* __restrict__ w3f) {
    int idx = blockIdx.x * 256 + threadIdx.x;   // 0..49151
    int lane = (idx >> 3) & 63, e = idx & 7;
    int l = lane & 15, gg = lane >> 4;
    if (idx < 16384) {
        int fi = idx >> 9, n = fi >> 2, ks = fi & 3;
        int k = ks * 32 + gg * 8 + e;
        w1f[idx] = (__bf16)w1[k * DD + n * 16 + l];
    } else {
        int j = idx - 16384;
        int fi = j >> 9, n = fi >> 3, ks = fi & 7;
        int k = ks * 32 + gg * 8 + e;
        w3f[j] = (__bf16)w3[k * DD + n * 16 + l];
    }
}

// ---- K1: 4 bn per block (256 thr, 4 waves), 3 phases, 2 barriers.
// Phase 1: block-coop stage A = bf16(ave*adj) AND raw adj bf16 -> swizzled LDS.
// Phase 2: 48 rows = exactly 3 MFMA tiles; waves 0..2 one tile each (no pad rows);
//          B-frags per-ks from w1f (8 frags live -> low VGPR).
// Phase 3: wave w -> bn w: softmax (redundant per-lane) + att from LDS columns.
__launch_bounds__(256, 4)
__global__ void k_att(const float* __restrict__ ave, const float* __restrict__ adj,
                      const float* __restrict__ wgt, const float* __restrict__ w1,
                      const float* __restrict__ w2, const __bf16* __restrict__ w1f,
                      float* __restrict__ att_out) {
    __shared__ unsigned char lds[2 * 48 * 256 + 48 * 4];   // 24.2 KB
    unsigned char* Ab   = lds;                  // 48 rows x 256B  A = ave*adj, swizzled
    unsigned char* adjb = lds + 12288;          // 48 rows x 256B  raw adj, swizzled
    float* sco = (float*)(lds + 24576);         // 48 scores (R0-relative row order)

    const int t = threadIdx.x;
    const int lane = t & 63;
    const int w = t >> 6;                 // 0..3
    const int l = lane & 15, g = lane >> 4;
    const int Bn0 = blockIdx.x * 4;
    const size_t R0 = (size_t)Bn0 * KADJ; // global flat adj-row base

    // ---- phase 1: stage 48 rows; multiply by ave here (f32, single rounding) ----
    #pragma unroll
    for (int i = 0; i < 3; ++i) {
        int idx = i * 256 + t;            // 0..767 = 48 rows x 16 chunks
        int row = idx >> 4, c8 = idx & 15;
        int bl = row / 12;                // local bn of this row
        const float* gs = adj + (R0 + row) * (size_t)DD + c8 * 8;
        f32x4 v0 = *reinterpret_cast<const f32x4*>(gs);
        f32x4 v1 = *reinterpret_cast<const f32x4*>(gs + 4);
        const float* as = ave + (size_t)(Bn0 + bl) * DD + c8 * 8;
        f32x4 e0 = *reinterpret_cast<const f32x4*>(as);
        f32x4 e1 = *reinterpret_cast<const f32x4*>(as + 4);
        int off = row * 256 + ((c8 ^ (row & 15)) << 4);
        *reinterpret_cast<bf16x8*>(adjb + off) = cvt8(v0, v1);
        *reinterpret_cast<bf16x8*>(Ab + off)   = cvt8(v0 * e0, v1 * e1);
    }
    __syncthreads();

    // ---- phase 2: waves 0..2, tile w = rows w*16..w*16+15 (all real) ----
    if (w < 3) {
        const int lr = w * 16 + l;
        f32x4 acc[8];
        #pragma unroll
        for (int n = 0; n < 8; ++n) acc[n] = f32x4{0.f, 0.f, 0.f, 0.f};
        #pragma unroll 1
        for (int ks = 0; ks < 4; ++ks) {
            bf16x8 bq[8];
            #pragma unroll
            for (int n = 0; n < 8; ++n)
                bq[n] = *reinterpret_cast<const bf16x8*>(
                    w1f + ((size_t)(n * 4 + ks) * 512 + lane * 8));
            bf16x8 af = *reinterpret_cast<const bf16x8*>(
                Ab + lr * 256 + (((ks * 4 + g) ^ (lr & 15)) << 4));
            #pragma unroll
            for (int n = 0; n < 8; ++n)
                acc[n] = __builtin_amdgcn_mfma_f32_16x16x32_bf16(af, bq[n], acc[n], 0, 0, 0);
        }
        // epilogue: rank-1 wgt column, leaky, dot w2 (operands L1-hot, in-loop = low VGPR)
        float wv[4];
        #pragma unroll
        for (int j = 0; j < 4; ++j)
            wv[j] = wgt[R0 + (size_t)w * 16 + g * 4 + j];
        float p[4] = {0.f, 0.f, 0.f, 0.f};
        #pragma unroll
        for (int n = 0; n < 8; ++n) {
            float w1rn = w1[128 * DD + n * 16 + l];   // w1 row 128 = concat'd wgt row
            float w2vn = w2[n * 16 + l];
            #pragma unroll
            for (int j = 0; j < 4; ++j) {
                float h = fmaf(wv[j], w1rn, acc[n][j]);
                h = h > 0.f ? h : 0.2f * h;
                p[j] = fmaf(h, w2vn, p[j]);
            }
        }
        #pragma unroll
        for (int j = 0; j < 4; ++j) {
            p[j] += __shfl_xor(p[j], 1, 64);
            p[j] += __shfl_xor(p[j], 2, 64);
            p[j] += __shfl_xor(p[j], 4, 64);
            p[j] += __shfl_xor(p[j], 8, 64);
        }
        if (l == 0)
            *reinterpret_cast<f32x4*>(&sco[w * 16 + g * 4]) =
                f32x4{p[0], p[1], p[2], p[3]};
    }
    __syncthreads();

    // ---- phase 3: softmax + att. wave w -> bn w; lane -> cols {2*lane, 2*lane+1} ----
    {
        float s[KADJ];
        float mx = -1e30f;
        #pragma unroll
        for (int k = 0; k < KADJ; ++k) { s[k] = sco[w * 12 + k]; mx = fmaxf(mx, s[k]); }
        float ssum = 0.f;
        #pragma unroll
        for (int k = 0; k < KADJ; ++k) { s[k] = __expf(s[k] - mx); ssum += s[k]; }
        float inv = 1.f / ssum;
        float a0 = 0.f, a1 = 0.f;
        #pragma unroll
        for (int k = 0; k < KADJ; ++k) {
            int row = w * 12 + k;
            u32 pk = *reinterpret_cast<const u32*>(
                adjb + row * 256 + (((lane >> 2) ^ (row & 15)) << 4) + (lane & 3) * 4);
            float alpha = s[k] * inv;
            float e0 = __builtin_bit_cast(float, pk << 16);
            float e1 = __builtin_bit_cast(float, pk & 0xFFFF0000u);
            a0 = fmaf(alpha, e0, a0);
            a1 = fmaf(alpha, e1, a1);
        }
        *reinterpret_cast<f32x2*>(att_out + (size_t)(Bn0 + w) * DD + lane * 2) =
            f32x2{a0, a1};
    }
}

// ---- K2: out = relu([itm | att] @ w3) via MFMA; B-frags coalesced from w3f ----
__launch_bounds__(256)
__global__ void k_out(const float* __restrict__ itm, const float* att,
                      const __bf16* __restrict__ w3f, float* outp) {
    const int t = threadIdx.x;
    const int lane = t & 63;
    const int w = t >> 6;
    const int l = lane & 15, g = lane >> 4;
    const int R0 = blockIdx.x * 64 + w * 16;
    const int row = R0 + l;

    bf16x8 afr[8];
    const float* ip = itm + (size_t)row * DD;
    #pragma unroll
    for (int s = 0; s < 4; ++s) {
        int c = s * 32 + g * 8;
        f32x4 a0 = *reinterpret_cast<const f32x4*>(ip + c);
        f32x4 a1 = *reinterpret_cast<const f32x4*>(ip + c + 4);
        afr[s] = cvt8(a0, a1);
    }
    const float* ap = att + (size_t)row * DD;
    #pragma unroll
    for (int s = 0; s < 4; ++s) {
        int c = s * 32 + g * 8;
        f32x4 a0 = *reinterpret_cast<const f32x4*>(ap + c);
        f32x4 a1 = *reinterpret_cast<const f32x4*>(ap + c + 4);
        afr[4 + s] = cvt8(a0, a1);
    }

    f32x4 acc[8];
    #pragma unroll
    for (int n = 0; n < 8; ++n) acc[n] = f32x4{0.f, 0.f, 0.f, 0.f};
    #pragma unroll
    for (int s = 0; s < 8; ++s) {
        const __bf16* bp = w3f + ((size_t)s * 64 + lane) * 8;    // coalesced 1KB/wave
        #pragma unroll
        for (int n = 0; n < 8; ++n) {
            bf16x8 bfr = *reinterpret_cast<const bf16x8*>(bp + (size_t)n * 4096);
            acc[n] = __builtin_amdgcn_mfma_f32_16x16x32_bf16(afr[s], bfr, acc[n], 0, 0, 0);
        }
    }

    #pragma unroll
    for (int n = 0; n < 8; ++n) {
        #pragma unroll
        for (int j = 0; j < 4; ++j)
            outp[(size_t)(R0 + g * 4 + j) * DD + n * 16 + l] = fmaxf(acc[n][j], 0.f);
    }
}

extern "C" void kernel_launch(void* const* d_in, const int* in_sizes, int n_in,
                              void* d_out, int out_size, void* d_ws, size_t ws_size,
                              hipStream_t stream) {
    const float* itm = (const float*)d_in[1];
    const float* ave = (const float*)d_in[2];
    const float* adj = (const float*)d_in[3];
    const float* wgt = (const float*)d_in[4];
    const float* w1  = (const float*)d_in[5];
    const float* w2  = (const float*)d_in[6];
    const float* w3  = (const float*)d_in[7];
    float* outp = (float*)d_out;

    __bf16* w1f = (__bf16*)d_ws;                       // 32 KB, fragment-ordered
    __bf16* w3f = (__bf16*)((char*)d_ws + 32 * 1024);  // 64 KB, fragment-ordered

    k_prep<<<dim3(192), dim3(256), 0, stream>>>(w1, w3, w1f, w3f);
    k_att<<<dim3(BN_TOTAL / 4), dim3(256), 0, stream>>>(ave, adj, wgt, w1, w2, w1f, outp);
    k_out<<<dim3(BN_TOTAL / 64), dim3(256), 0, stream>>>(itm, outp, w3f, outp);
}